// Round 1
// baseline (337.922 us; speedup 1.0000x reference)
//
#include <hip/hip_runtime.h>
#include <math.h>

// ---------------------------------------------------------------------------
// KAN-Conv CIFAR net on gfx950, round 6.
// vs round 5 (169.7us): the conv main loop was LDS-issue-bound (~168 LDS-pipe
// cyc/wave-f vs ~66 VALU cyc/wave-f on a per-CU basis) and latency-starved
// (L3: 1 block/CU = 4 waves).  Changes:
//  (1) register row-sliding per channel: ky fully unrolled, 2-slot act row
//      cache -> 32 ds_read_b128 per (c,thread) instead of 72 (-56%).
//  (2) weights for ALL layers via wave-uniform global float4 loads with an
//      explicit 1-step-ahead double-buffer prefetch; sched_barrier(0) per
//      tap bounds in-flight loads to 8 (replaces unroll-1-ky, which would
//      force dynamic reg indexing -> scratch).  L1 weights leave the LDS
//      pipe entirely; WLDS path removed.
//  (3) L3: FS=4, NT=512 -> 8 waves/CU instead of 4.  f-split reduction
//      buffer aliases the merged (lo|hi) act arena.
// ---------------------------------------------------------------------------

#define BATCH 256

__device__ __forceinline__ void bspline_basis(float x, float bs[6]) {
    const float h = 2.0f / 3.0f;
    float g[10];
#pragma unroll
    for (int i = 0; i < 10; ++i) g[i] = (float)(i - 3) * h - 1.0f;
    float b[9];
#pragma unroll
    for (int i = 0; i < 9; ++i) b[i] = (x >= g[i] && x < g[i + 1]) ? 1.0f : 0.0f;
#pragma unroll
    for (int j = 1; j <= 3; ++j) {
        const float inv_d = 1.0f / ((float)j * h);
#pragma unroll
        for (int i = 0; i + j < 9; ++i) {
            float left  = (x - g[i]) * inv_d;
            float right = (g[i + j + 1] - x) * inv_d;
            b[i] = left * b[i] + right * b[i + 1];
        }
    }
#pragma unroll
    for (int i = 0; i < 6; ++i) bs[i] = b[i];
}

// Fuse {base_w, spline_w*scaler} into 8-float records for all three layers.
__global__ __launch_bounds__(256) void prep_weights(
        const float* __restrict__ bw1, const float* __restrict__ sw1, const float* __restrict__ sc1,
        const float* __restrict__ bw2, const float* __restrict__ sw2, const float* __restrict__ sc2,
        const float* __restrict__ bw3, const float* __restrict__ sw3, const float* __restrict__ sc3,
        float* __restrict__ w1, float* __restrict__ w2, float* __restrict__ w3) {
    int i = blockIdx.x * blockDim.x + threadIdx.x;
    const float *bw, *sw, *sc;
    float* dst;
    int j;
    if (i < 216)       { bw = bw1; sw = sw1; sc = sc1; dst = w1; j = i; }
    else if (i < 1368) { bw = bw2; sw = sw2; sc = sc2; dst = w2; j = i - 216; }
    else if (i < 5976) { bw = bw3; sw = sw3; sc = sc3; dst = w3; j = i - 1368; }
    else return;
    float s = sc[j];
    float4* o = (float4*)(dst + (size_t)j * 8);
    o[0] = make_float4(bw[j], sw[j * 6 + 0] * s, sw[j * 6 + 1] * s, sw[j * 6 + 2] * s);
    o[1] = make_float4(sw[j * 6 + 3] * s, sw[j * 6 + 4] * s, sw[j * 6 + 5] * s, 0.0f);
}

// Fused: basis precompute (LDS) + KAN conv3x3(pad1) + maxpool2.
// x: [B,C,H,W]; wrec: [O, C*9, 8] fused; out: [B,O,H/2,W/2].
// VS: vertical split of pooled rows across blocks. FS: channel split within
// block (LDS-reduced).
template <int C, int O, int GO, int H, int W, int VS, int FS, int NT>
__global__ __launch_bounds__(NT, 2) void kan_conv_pool(
        const float* __restrict__ x,
        const float* __restrict__ wrec,
        float* __restrict__ out) {
    constexpr int PH = H / 2, PW = W / 2;
    constexpr int PR = PH / VS;            // pooled rows per block
    constexpr int R  = 2 * PR + 2;         // input tile rows (incl. halo)
    constexpr int TC = W + 2;              // input tile cols (incl. halo)
    constexpr int CP = TC / 2;             // cols per parity plane
    constexpr int F  = C * 9;
    constexpr int PPB = PR * PW;           // pooled pixels per block
    constexpr int NOG = O / GO;
    constexpr int CS = C / FS;             // channels per f-slice
    constexpr int CPLANE = R * 2 * CP;     // float4s per channel plane
    constexpr int HALF = C * CPLANE;       // lo-arena size
    static_assert(NT == NOG * FS * PPB, "thread mapping");

    // Merged act arena: lo at [0,HALF), hi at [HALF, 2*HALF).
    // Per-elem index ((c*R + row)*2 + parity)*CP + col/2.
    __shared__ float4 s_act[2 * HALF];

    const int tid = threadIdx.x;
    const int bid = blockIdx.x;
    const int b = (VS > 1) ? (bid / VS) : bid;
    const int v = (VS > 1) ? (bid % VS) : 0;
    const int r0 = v * (2 * PR) - 1;       // global row of tile row 0

    // ---- Stage: zero-padded x -> [silu, b0..b5] records in LDS
    const float* xb = x + (size_t)b * C * H * W;
    for (int i = tid; i < C * R * TC; i += NT) {
        int cc  = i / (R * TC);
        int rr  = (i / TC) % R;
        int col = i % TC;
        int gr = r0 + rr, gc = col - 1;
        float val = 0.0f;
        if ((unsigned)gr < (unsigned)H && (unsigned)gc < (unsigned)W)
            val = xb[(cc * H + gr) * W + gc];
        float silu = val / (1.0f + __expf(-val));
        float bs[6];
        bspline_basis(val, bs);
        int idx = ((cc * R + rr) * 2 + (col & 1)) * CP + (col >> 1);
        s_act[idx]        = make_float4(silu, bs[0], bs[1], bs[2]);
        s_act[HALF + idx] = make_float4(bs[3], bs[4], bs[5], 0.0f);
    }
    __syncthreads();

    // ---- Thread mapping
    const int px = tid % PPB;
    const int fh = (tid / PPB) % FS;
    const int og = tid / (PPB * FS);
    const int phl = px / PW, pw = px % PW;
    const int o0 = og * GO;

    float acc[GO][4];
#pragma unroll
    for (int g = 0; g < GO; ++g)
#pragma unroll
        for (int p = 0; p < 4; ++p) acc[g][p] = 0.f;

#pragma unroll 1
    for (int cc = 0; cc < CS; ++cc) {
        const int c = fh * CS + cc;
        // plo/phi point at this thread's pooled-window origin within channel c.
        const float4* plo = s_act + c * CPLANE + (2 * phl) * (2 * CP) + pw;
        const float4* phi = plo + HALF;
        // weight base for (o0, f = c*9): record (o,f) = 2 float4s.
        const float4* wq = (const float4*)wrec + ((size_t)o0 * F + c * 9) * 2;

        // 2-slot sliding row cache (rows r = ky+dy, r in 0..3, cols s in 0..3)
        float4 alo[2][4], ahi[2][4];
        // double-buffered weight prefetch (one tap = GO * {lo,hi})
        float4 wlb[2][GO], whb[2][GO];

#define LOADROW(sl, r) { \
        const int rb_ = (r) * (2 * CP); \
        alo[sl][0] = plo[rb_];          ahi[sl][0] = phi[rb_]; \
        alo[sl][1] = plo[rb_ + CP];     ahi[sl][1] = phi[rb_ + CP]; \
        alo[sl][2] = plo[rb_ + 1];      ahi[sl][2] = phi[rb_ + 1]; \
        alo[sl][3] = plo[rb_ + CP + 1]; ahi[sl][3] = phi[rb_ + CP + 1]; }

#define WLOAD(buf, df) { \
        _Pragma("unroll") \
        for (int g = 0; g < GO; ++g) { \
            wlb[buf][g] = wq[(size_t)g * (F * 2) + (df) * 2]; \
            whb[buf][g] = wq[(size_t)g * (F * 2) + (df) * 2 + 1]; } }

        // One tap: 4 pool positions (dy via row slots d0/d1, dx in 0..1).
#define FSTEP(buf, kx, d0, d1) { \
        _Pragma("unroll") \
        for (int g = 0; g < GO; ++g) { \
            const float4 wl_ = wlb[buf][g]; \
            const float4 wh_ = whb[buf][g]; \
            _Pragma("unroll") \
            for (int dx = 0; dx < 2; ++dx) { \
                float4 lo0 = alo[d0][(kx) + dx], hi0 = ahi[d0][(kx) + dx]; \
                acc[g][dx] += lo0.x * wl_.x + lo0.y * wl_.y + lo0.z * wl_.z + \
                              lo0.w * wl_.w + hi0.x * wh_.x + hi0.y * wh_.y + \
                              hi0.z * wh_.z; \
                float4 lo1 = alo[d1][(kx) + dx], hi1 = ahi[d1][(kx) + dx]; \
                acc[g][2 + dx] += lo1.x * wl_.x + lo1.y * wl_.y + lo1.z * wl_.z + \
                                  lo1.w * wl_.w + hi1.x * wh_.x + hi1.y * wh_.y + \
                                  hi1.z * wh_.z; } } }

        // Prologue: tap f0 weights + rows 0,1.
        WLOAD(0, 0)
        LOADROW(0, 0)
        LOADROW(1, 1)
        // ky=0 (rows slot0=r0, slot1=r1)
        WLOAD(1, 1) FSTEP(0, 0, 0, 1) __builtin_amdgcn_sched_barrier(0);
        WLOAD(0, 2) FSTEP(1, 1, 0, 1) __builtin_amdgcn_sched_barrier(0);
        WLOAD(1, 3) FSTEP(0, 2, 0, 1) LOADROW(0, 2) __builtin_amdgcn_sched_barrier(0);
        // ky=1 (slot1=r1, slot0=r2)
        WLOAD(0, 4) FSTEP(1, 0, 1, 0) __builtin_amdgcn_sched_barrier(0);
        WLOAD(1, 5) FSTEP(0, 1, 1, 0) __builtin_amdgcn_sched_barrier(0);
        WLOAD(0, 6) FSTEP(1, 2, 1, 0) LOADROW(1, 3) __builtin_amdgcn_sched_barrier(0);
        // ky=2 (slot0=r2, slot1=r3)
        WLOAD(1, 7) FSTEP(0, 0, 0, 1) __builtin_amdgcn_sched_barrier(0);
        WLOAD(0, 8) FSTEP(1, 1, 0, 1) __builtin_amdgcn_sched_barrier(0);
        FSTEP(0, 2, 0, 1) __builtin_amdgcn_sched_barrier(0);
#undef LOADROW
#undef WLOAD
#undef FSTEP
    }

    // ---- f-split reduction (reduce buffer aliases the merged act arena)
    if (FS > 1) {
        float4* s_red = s_act;
        static_assert(FS == 1 || NT * GO <= 2 * HALF, "red fits");
        __syncthreads();                   // act reads done before overwrite
#pragma unroll
        for (int g = 0; g < GO; ++g)
            s_red[tid * GO + g] = make_float4(acc[g][0], acc[g][1], acc[g][2], acc[g][3]);
        __syncthreads();
        if (fh != 0) return;
#pragma unroll
        for (int fq = 1; fq < FS; ++fq)
#pragma unroll
            for (int g = 0; g < GO; ++g) {
                float4 t = s_red[(tid + fq * PPB) * GO + g];
                acc[g][0] += t.x; acc[g][1] += t.y; acc[g][2] += t.z; acc[g][3] += t.w;
            }
    }

    // ---- maxpool + store
    const int phg = v * PR + phl;
#pragma unroll
    for (int g = 0; g < GO; ++g) {
        float m = fmaxf(fmaxf(acc[g][0], acc[g][1]), fmaxf(acc[g][2], acc[g][3]));
        out[(((size_t)b * O + o0 + g) * PH + phg) * PW + pw] = m;
    }
}

// out[n,o] = dot(h[n,:512], w[o,:512]) + bias[o]
__global__ __launch_bounds__(256) void linear_kernel(const float* __restrict__ h,
                                                     const float* __restrict__ w,
                                                     const float* __restrict__ bias,
                                                     float* __restrict__ out) {
    int idx = blockIdx.x * blockDim.x + threadIdx.x;
    if (idx >= BATCH * 100) return;
    int o = idx % 100;
    int n = idx / 100;
    const float4* hp = (const float4*)(h + (size_t)n * 512);
    const float4* wp = (const float4*)(w + (size_t)o * 512);
    float acc = 0.f;
#pragma unroll 4
    for (int i = 0; i < 128; ++i) {
        float4 a = hp[i];
        float4 b = wp[i];
        acc += a.x * b.x + a.y * b.y + a.z * b.z + a.w * b.w;
    }
    out[idx] = acc + bias[o];
}

extern "C" void kernel_launch(void* const* d_in, const int* in_sizes, int n_in,
                              void* d_out, int out_size, void* d_ws, size_t ws_size,
                              hipStream_t stream) {
    const float* x     = (const float*)d_in[0];
    const float* c1_bw = (const float*)d_in[1];
    const float* c1_sw = (const float*)d_in[2];
    const float* c1_sc = (const float*)d_in[3];
    const float* c2_bw = (const float*)d_in[4];
    const float* c2_sw = (const float*)d_in[5];
    const float* c2_sc = (const float*)d_in[6];
    const float* c3_bw = (const float*)d_in[7];
    const float* c3_sw = (const float*)d_in[8];
    const float* c3_sc = (const float*)d_in[9];
    const float* lin_w = (const float*)d_in[10];
    const float* lin_b = (const float*)d_in[11];
    float* out = (float*)d_out;

    float* ws = (float*)d_ws;
    float* h1 = ws;                 // 256*8*16*16  = 524288
    float* h2 = h1 + 524288;        // 256*16*8*8   = 262144
    float* h3 = h2 + 262144;        // 256*32*4*4   = 131072
    float* w1 = h3 + 131072;        // 216*8  = 1728
    float* w2 = w1 + 1728;          // 1152*8 = 9216
    float* w3 = w2 + 9216;          // 4608*8 = 36864
    // total 965312 floats = 3.9 MB

    // Fused weight records (independent; launch first).
    prep_weights<<<24, 256, 0, stream>>>(
        c1_bw, c1_sw, c1_sc, c2_bw, c2_sw, c2_sc, c3_bw, c3_sw, c3_sc, w1, w2, w3);

    // L1: [256,3,32,32] -> [256,8,16,16]; GO=4. 512 blocks x 256.
    kan_conv_pool<3, 8, 4, 32, 32, 2, 1, 256><<<512, 256, 0, stream>>>(x, w1, h1);
    // L2: [256,8,16,16] -> [256,16,8,8]; GO=4, FS=2. 512 blocks x 256.
    kan_conv_pool<8, 16, 4, 16, 16, 2, 2, 256><<<512, 256, 0, stream>>>(h1, w2, h2);
    // L3: [256,16,8,8] -> [256,32,4,4]; GO=4, FS=4. 256 blocks x 512 (8 waves/CU).
    kan_conv_pool<16, 32, 4, 8, 8, 1, 4, 512><<<256, 512, 0, stream>>>(h2, w3, h3);
    // Linear: [256,512] @ [100,512]^T + b.
    linear_kernel<<<100, 256, 0, stream>>>(h3, lin_w, lin_b, out);
}

// Round 2
// 172.389 us; speedup vs baseline: 1.9602x; 1.9602x over previous
//
#include <hip/hip_runtime.h>
#include <math.h>

// ---------------------------------------------------------------------------
// KAN-Conv CIFAR net on gfx950, round 7.
// Round 6 (row-cache + dbuf weights + sched_barrier pinning) spilled to
// scratch (139MB fetch / 272MB write per conv) -> 338us. Reverted to the
// round-5 structure (169.7us) with three bounded changes:
//  (1) GO=8 on L2/L3 (was 4): act ds_read_b128 amortized over 8 outputs ->
//      total act LDS reads halved at constant FMAs; only +16 VGPR (acc).
//      LDS-pipe oversubscription drops ~1.7x -> ~0.86x (VALU-bound).
//  (2) #pragma unroll 1 on cc, ky AND kx: bounds the scheduler's global-load
//      hoisting window to one tap (GO*2 float4 in flight) -- the register-
//      pressure fence that round 6's sched_barrier failed to be.
//  (3) weights re-laid out as [F][O] (tap-major): one base addr per tap,
//      GO records at small immediate offsets. FS-reduction buffer layout
//      [g*NT+tid] (stride-1 per lane) instead of [tid*GO+g] (all lanes in
//      bank 0).
// L1 keeps the round-5 config (GO=4, WLDS=1).
// ---------------------------------------------------------------------------

#define BATCH 256

struct W3 { float x, y, z; };   // packed 12-byte LDS record

__device__ __forceinline__ void bspline_basis(float x, float bs[6]) {
    const float h = 2.0f / 3.0f;
    float g[10];
#pragma unroll
    for (int i = 0; i < 10; ++i) g[i] = (float)(i - 3) * h - 1.0f;
    float b[9];
#pragma unroll
    for (int i = 0; i < 9; ++i) b[i] = (x >= g[i] && x < g[i + 1]) ? 1.0f : 0.0f;
#pragma unroll
    for (int j = 1; j <= 3; ++j) {
        const float inv_d = 1.0f / ((float)j * h);
#pragma unroll
        for (int i = 0; i + j < 9; ++i) {
            float left  = (x - g[i]) * inv_d;
            float right = (g[i + j + 1] - x) * inv_d;
            b[i] = left * b[i] + right * b[i + 1];
        }
    }
#pragma unroll
    for (int i = 0; i < 6; ++i) bs[i] = b[i];
}

// Fuse {base_w, spline_w*scaler} into 8-float records, tap-major [F][O][8].
__global__ __launch_bounds__(256) void prep_weights(
        const float* __restrict__ bw1, const float* __restrict__ sw1, const float* __restrict__ sc1,
        const float* __restrict__ bw2, const float* __restrict__ sw2, const float* __restrict__ sc2,
        const float* __restrict__ bw3, const float* __restrict__ sw3, const float* __restrict__ sc3,
        float* __restrict__ w1, float* __restrict__ w2, float* __restrict__ w3) {
    int i = blockIdx.x * blockDim.x + threadIdx.x;
    const float *bw, *sw, *sc;
    float* dst;
    int j, O, F;
    if (i < 216)       { bw = bw1; sw = sw1; sc = sc1; dst = w1; j = i;        O = 8;  F = 27;  }
    else if (i < 1368) { bw = bw2; sw = sw2; sc = sc2; dst = w2; j = i - 216;  O = 16; F = 72;  }
    else if (i < 5976) { bw = bw3; sw = sw3; sc = sc3; dst = w3; j = i - 1368; O = 32; F = 144; }
    else return;
    int o = j / F, fi = j % F;            // input is [O,F] row-major
    float s = sc[j];
    float4* dq = (float4*)(dst + (size_t)(fi * O + o) * 8);
    dq[0] = make_float4(bw[j], sw[j * 6 + 0] * s, sw[j * 6 + 1] * s, sw[j * 6 + 2] * s);
    dq[1] = make_float4(sw[j * 6 + 3] * s, sw[j * 6 + 4] * s, sw[j * 6 + 5] * s, 0.0f);
}

// Fused: basis precompute (LDS) + KAN conv3x3(pad1) + maxpool2.
// x: [B,C,H,W]; wrec: [C*9, O, 8] fused; out: [B,O,H/2,W/2].
// VS: vertical split of pooled rows across blocks. FS: channel split within
// block (LDS-reduced). WLDS: stage weights in LDS (only fits for layer 1).
template <int C, int O, int GO, int H, int W, int VS, int FS, int NT, int WLDS>
__global__ __launch_bounds__(NT, 2) void kan_conv_pool(
        const float* __restrict__ x,
        const float* __restrict__ wrec,
        float* __restrict__ out) {
    constexpr int PH = H / 2, PW = W / 2;
    constexpr int PR = PH / VS;            // pooled rows per block
    constexpr int R  = 2 * PR + 2;         // input tile rows (incl. halo)
    constexpr int TC = W + 2;              // input tile cols (incl. halo)
    constexpr int CP = TC / 2;             // cols per parity plane
    constexpr int F  = C * 9;
    constexpr int PPB = PR * PW;           // pooled pixels per block
    constexpr int NOG = O / GO;
    constexpr int CS = C / FS;             // channels per f-slice
    constexpr int CPLANE = R * 2 * CP;     // float4s per channel plane
    constexpr int HALF = C * CPLANE;       // lo-arena size
    static_assert(NT == NOG * FS * PPB, "thread mapping");
    static_assert(FS * CS == C, "channel split");

    // Merged act arena: lo at [0,HALF), hi at [HALF,2*HALF).
    // Per-elem index ((c*R + row)*2 + parity)*CP + col/2.
    __shared__ float4 s_act[2 * HALF];
    constexpr int NWR = WLDS ? O * F : 1;
    __shared__ float4 s_wlo[NWR];
    __shared__ W3     s_whi[NWR];

    const int tid = threadIdx.x;
    const int bid = blockIdx.x;
    const int b = (VS > 1) ? (bid / VS) : bid;
    const int v = (VS > 1) ? (bid % VS) : 0;
    const int r0 = v * (2 * PR) - 1;       // global row of tile row 0

    // ---- Stage: zero-padded x -> [silu, b0..b5] records in LDS
    const float* xb = x + (size_t)b * C * H * W;
    for (int i = tid; i < C * R * TC; i += NT) {
        int cc  = i / (R * TC);
        int rr  = (i / TC) % R;
        int col = i % TC;
        int gr = r0 + rr, gc = col - 1;
        float val = 0.0f;
        if ((unsigned)gr < (unsigned)H && (unsigned)gc < (unsigned)W)
            val = xb[(cc * H + gr) * W + gc];
        float silu = val / (1.0f + __expf(-val));
        float bs[6];
        bspline_basis(val, bs);
        int idx = ((cc * R + rr) * 2 + (col & 1)) * CP + (col >> 1);
        s_act[idx]        = make_float4(silu, bs[0], bs[1], bs[2]);
        s_act[HALF + idx] = make_float4(bs[3], bs[4], bs[5], 0.0f);
    }
    if (WLDS) {
        for (int j = tid; j < O * F; j += NT) {
            const float4* wp = (const float4*)(wrec + (size_t)j * 8);
            float4 lo = wp[0], hi = wp[1];
            s_wlo[j] = lo;
            W3 t; t.x = hi.x; t.y = hi.y; t.z = hi.z;
            s_whi[j] = t;
        }
    }
    __syncthreads();

    // ---- Thread mapping
    const int px = tid % PPB;
    const int fh = (tid / PPB) % FS;
    const int og = tid / (PPB * FS);
    const int phl = px / PW, pw = px % PW;
    const int o0 = og * GO;

    float acc[GO][4];
#pragma unroll
    for (int g = 0; g < GO; ++g)
#pragma unroll
        for (int p = 0; p < 4; ++p) acc[g][p] = 0.f;

    const int pbase = (2 * phl) * (2 * CP) + pw;

#pragma unroll 1
    for (int cc = 0; cc < CS; ++cc) {
        const int c = fh * CS + cc;
        const float4* plo = s_act + c * CPLANE;
        const float4* phi = plo + HALF;
#pragma unroll 1
        for (int ky = 0; ky < 3; ++ky) {
#pragma unroll 1
            for (int kx = 0; kx < 3; ++kx) {
                const int f = c * 9 + ky * 3 + kx;
                float4 wl[GO];
                float  whx[GO], why[GO], whz[GO];
                if (WLDS) {
#pragma unroll
                    for (int g = 0; g < GO; ++g) {
                        const int r = f * O + o0 + g;
                        wl[g] = s_wlo[r];
                        W3 t = s_whi[r];
                        whx[g] = t.x; why[g] = t.y; whz[g] = t.z;
                    }
                } else {
                    const float4* wp = (const float4*)wrec + (size_t)(f * O + o0) * 2;
#pragma unroll
                    for (int g = 0; g < GO; ++g) {
                        wl[g] = wp[g * 2];
                        float4 hv = wp[g * 2 + 1];
                        whx[g] = hv.x; why[g] = hv.y; whz[g] = hv.z;
                    }
                }
#pragma unroll
                for (int dy = 0; dy < 2; ++dy) {
#pragma unroll
                    for (int dx = 0; dx < 2; ++dx) {
                        const int s = dx + kx;
                        const int off = pbase + ((dy + ky) * 2 + (s & 1)) * CP + (s >> 1);
                        float4 lo = plo[off];
                        float4 hi = phi[off];
#pragma unroll
                        for (int g = 0; g < GO; ++g) {
                            acc[g][dy * 2 + dx] +=
                                lo.x * wl[g].x + lo.y * wl[g].y + lo.z * wl[g].z +
                                lo.w * wl[g].w + hi.x * whx[g] + hi.y * why[g] +
                                hi.z * whz[g];
                        }
                    }
                }
            }
        }
    }

    // ---- f-split reduction (reduce buffer aliases the merged act arena)
    if (FS > 1) {
        float4* s_red = s_act;
        static_assert(FS == 1 || NT * GO <= 2 * HALF, "red fits");
        __syncthreads();                   // act reads done before overwrite
#pragma unroll
        for (int g = 0; g < GO; ++g)
            s_red[g * NT + tid] = make_float4(acc[g][0], acc[g][1], acc[g][2], acc[g][3]);
        __syncthreads();
        if (fh != 0) return;
#pragma unroll
        for (int fq = 1; fq < FS; ++fq)
#pragma unroll
            for (int g = 0; g < GO; ++g) {
                float4 t = s_red[g * NT + tid + fq * PPB];
                acc[g][0] += t.x; acc[g][1] += t.y; acc[g][2] += t.z; acc[g][3] += t.w;
            }
    }

    // ---- maxpool + store
    const int phg = v * PR + phl;
#pragma unroll
    for (int g = 0; g < GO; ++g) {
        float m = fmaxf(fmaxf(acc[g][0], acc[g][1]), fmaxf(acc[g][2], acc[g][3]));
        out[(((size_t)b * O + o0 + g) * PH + phg) * PW + pw] = m;
    }
}

// out[n,o] = dot(h[n,:512], w[o,:512]) + bias[o]
__global__ __launch_bounds__(256) void linear_kernel(const float* __restrict__ h,
                                                     const float* __restrict__ w,
                                                     const float* __restrict__ bias,
                                                     float* __restrict__ out) {
    int idx = blockIdx.x * blockDim.x + threadIdx.x;
    if (idx >= BATCH * 100) return;
    int o = idx % 100;
    int n = idx / 100;
    const float4* hp = (const float4*)(h + (size_t)n * 512);
    const float4* wp = (const float4*)(w + (size_t)o * 512);
    float acc = 0.f;
#pragma unroll 4
    for (int i = 0; i < 128; ++i) {
        float4 a = hp[i];
        float4 b = wp[i];
        acc += a.x * b.x + a.y * b.y + a.z * b.z + a.w * b.w;
    }
    out[idx] = acc + bias[o];
}

extern "C" void kernel_launch(void* const* d_in, const int* in_sizes, int n_in,
                              void* d_out, int out_size, void* d_ws, size_t ws_size,
                              hipStream_t stream) {
    const float* x     = (const float*)d_in[0];
    const float* c1_bw = (const float*)d_in[1];
    const float* c1_sw = (const float*)d_in[2];
    const float* c1_sc = (const float*)d_in[3];
    const float* c2_bw = (const float*)d_in[4];
    const float* c2_sw = (const float*)d_in[5];
    const float* c2_sc = (const float*)d_in[6];
    const float* c3_bw = (const float*)d_in[7];
    const float* c3_sw = (const float*)d_in[8];
    const float* c3_sc = (const float*)d_in[9];
    const float* lin_w = (const float*)d_in[10];
    const float* lin_b = (const float*)d_in[11];
    float* out = (float*)d_out;

    float* ws = (float*)d_ws;
    float* h1 = ws;                 // 256*8*16*16  = 524288
    float* h2 = h1 + 524288;        // 256*16*8*8   = 262144
    float* h3 = h2 + 262144;        // 256*32*4*4   = 131072
    float* w1 = h3 + 131072;        // 216*8  = 1728
    float* w2 = w1 + 1728;          // 1152*8 = 9216
    float* w3 = w2 + 9216;          // 4608*8 = 36864
    // total 965312 floats = 3.9 MB

    // Fused weight records (independent; launch first).
    prep_weights<<<24, 256, 0, stream>>>(
        c1_bw, c1_sw, c1_sc, c2_bw, c2_sw, c2_sc, c3_bw, c3_sw, c3_sc, w1, w2, w3);

    // L1: [256,3,32,32] -> [256,8,16,16]; GO=4, weights in LDS. 512 blocks.
    kan_conv_pool<3, 8, 4, 32, 32, 2, 1, 256, 1><<<512, 256, 0, stream>>>(x, w1, h1);
    // L2: [256,8,16,16] -> [256,16,8,8]; GO=8, FS=4. 512 blocks.
    kan_conv_pool<8, 16, 8, 16, 16, 2, 4, 256, 0><<<512, 256, 0, stream>>>(h1, w2, h2);
    // L3: [256,16,8,8] -> [256,32,4,4]; GO=8, FS=4. 256 blocks.
    kan_conv_pool<16, 32, 8, 8, 8, 1, 4, 256, 0><<<256, 256, 0, stream>>>(h2, w3, h3);
    // Linear: [256,512] @ [100,512]^T + b.
    linear_kernel<<<100, 256, 0, stream>>>(h3, lin_w, lin_b, out);
}

// Round 3
// 164.017 us; speedup vs baseline: 2.0603x; 1.0510x over previous
//
#include <hip/hip_runtime.h>
#include <math.h>

// ---------------------------------------------------------------------------
// KAN-Conv CIFAR net on gfx950, round 8.
// Evidence so far: r5=169.7us, r6(reg-cache,spilled)=337.9, r7(GO=8, -50% LDS
// act traffic)=172.4 (neutral) -> LDS throughput is NOT the limiter; convs
// run ~25% VALU-busy at 2 waves/SIMD -> latency-bound. This round raises
// occupancy only; inner loop untouched (round-5-proven GO=4 body):
//  (1) hi act record packed to 12B (W3): act LDS 28/32 -> L1 51.4KB,
//      L2 40.3KB, L3 44.8KB.
//  (2) L1: FS=3, NT=768 (12 waves/block -> 3/SIMD). L2: FS=4, NT=512,
//      2 blocks/CU -> 4/SIMD. L3: O-split OS=2 (grid 512), FS=8, NT=512,
//      2 blocks/CU -> 4/SIMD (was 1/SIMD!).
//  (3) launch_bounds(NT,4): VGPR<=128, GO=4 everywhere; WLDS dropped
//      (tap-major weights stay hot in L1/L2 cache).
// ---------------------------------------------------------------------------

#define BATCH 256

struct W3 { float x, y, z; };   // packed 12-byte LDS record

__device__ __forceinline__ void bspline_basis(float x, float bs[6]) {
    const float h = 2.0f / 3.0f;
    float g[10];
#pragma unroll
    for (int i = 0; i < 10; ++i) g[i] = (float)(i - 3) * h - 1.0f;
    float b[9];
#pragma unroll
    for (int i = 0; i < 9; ++i) b[i] = (x >= g[i] && x < g[i + 1]) ? 1.0f : 0.0f;
#pragma unroll
    for (int j = 1; j <= 3; ++j) {
        const float inv_d = 1.0f / ((float)j * h);
#pragma unroll
        for (int i = 0; i + j < 9; ++i) {
            float left  = (x - g[i]) * inv_d;
            float right = (g[i + j + 1] - x) * inv_d;
            b[i] = left * b[i] + right * b[i + 1];
        }
    }
#pragma unroll
    for (int i = 0; i < 6; ++i) bs[i] = b[i];
}

// Fuse {base_w, spline_w*scaler} into 8-float records, tap-major [F][O][8].
__global__ __launch_bounds__(256) void prep_weights(
        const float* __restrict__ bw1, const float* __restrict__ sw1, const float* __restrict__ sc1,
        const float* __restrict__ bw2, const float* __restrict__ sw2, const float* __restrict__ sc2,
        const float* __restrict__ bw3, const float* __restrict__ sw3, const float* __restrict__ sc3,
        float* __restrict__ w1, float* __restrict__ w2, float* __restrict__ w3) {
    int i = blockIdx.x * blockDim.x + threadIdx.x;
    const float *bw, *sw, *sc;
    float* dst;
    int j, O, F;
    if (i < 216)       { bw = bw1; sw = sw1; sc = sc1; dst = w1; j = i;        O = 8;  F = 27;  }
    else if (i < 1368) { bw = bw2; sw = sw2; sc = sc2; dst = w2; j = i - 216;  O = 16; F = 72;  }
    else if (i < 5976) { bw = bw3; sw = sw3; sc = sc3; dst = w3; j = i - 1368; O = 32; F = 144; }
    else return;
    int o = j / F, fi = j % F;            // input is [O,F] row-major
    float s = sc[j];
    float4* dq = (float4*)(dst + (size_t)(fi * O + o) * 8);
    dq[0] = make_float4(bw[j], sw[j * 6 + 0] * s, sw[j * 6 + 1] * s, sw[j * 6 + 2] * s);
    dq[1] = make_float4(sw[j * 6 + 3] * s, sw[j * 6 + 4] * s, sw[j * 6 + 5] * s, 0.0f);
}

// Fused: basis precompute (LDS) + KAN conv3x3(pad1) + maxpool2.
// x: [B,C,H,W]; wrec: [C*9, O, 8] fused; out: [B,O,H/2,W/2].
// VS: vertical split of pooled rows across blocks. OS: output-channel split
// across blocks. FS: channel split within block (LDS-reduced).
template <int C, int O, int GO, int H, int W, int VS, int OS, int FS, int NT, int MINW>
__global__ __launch_bounds__(NT, MINW) void kan_conv_pool(
        const float* __restrict__ x,
        const float* __restrict__ wrec,
        float* __restrict__ out) {
    constexpr int PH = H / 2, PW = W / 2;
    constexpr int PR = PH / VS;            // pooled rows per block
    constexpr int R  = 2 * PR + 2;         // input tile rows (incl. halo)
    constexpr int TC = W + 2;              // input tile cols (incl. halo)
    constexpr int CP = TC / 2;             // cols per parity plane
    constexpr int F  = C * 9;
    constexpr int PPB = PR * PW;           // pooled pixels per block
    constexpr int OPB = O / OS;            // output channels per block
    constexpr int NOG = OPB / GO;
    constexpr int CS = C / FS;             // channels per f-slice
    constexpr int CPLANE = R * 2 * CP;     // records per channel plane
    constexpr int HALF = C * CPLANE;       // records in act arena
    static_assert(NT == NOG * FS * PPB, "thread mapping");
    static_assert(FS * CS == C, "channel split");
    static_assert(NOG * GO == OPB && OPB * OS == O, "o split");

    // Act arena: float4 lo[HALF] then W3 hi[HALF]; FS-reduction buffer
    // aliases the whole arena.
    constexpr int ACT_BYTES = HALF * 16 + HALF * 12;
    constexpr int RED_BYTES = (FS > 1) ? NT * GO * 16 : 0;
    constexpr int ARENA = ACT_BYTES > RED_BYTES ? ACT_BYTES : RED_BYTES;
    static_assert(RED_BYTES <= ARENA, "red fits");
    __shared__ alignas(16) unsigned char s_mem[ARENA];
    float4* s_lo = (float4*)s_mem;
    W3*     s_hi = (W3*)(s_mem + (size_t)HALF * 16);

    const int tid = threadIdx.x;
    const int bid = blockIdx.x;
    const int b   = bid / (VS * OS);
    const int rem = bid % (VS * OS);
    const int v   = rem / OS;
    const int osb = rem % OS;
    const int r0 = v * (2 * PR) - 1;       // global row of tile row 0

    // ---- Stage: zero-padded x -> [silu, b0..b5] records in LDS
    const float* xb = x + (size_t)b * C * H * W;
    for (int i = tid; i < C * R * TC; i += NT) {
        int cc  = i / (R * TC);
        int rr  = (i / TC) % R;
        int col = i % TC;
        int gr = r0 + rr, gc = col - 1;
        float val = 0.0f;
        if ((unsigned)gr < (unsigned)H && (unsigned)gc < (unsigned)W)
            val = xb[(cc * H + gr) * W + gc];
        float silu = val / (1.0f + __expf(-val));
        float bs[6];
        bspline_basis(val, bs);
        int idx = ((cc * R + rr) * 2 + (col & 1)) * CP + (col >> 1);
        s_lo[idx] = make_float4(silu, bs[0], bs[1], bs[2]);
        W3 t; t.x = bs[3]; t.y = bs[4]; t.z = bs[5];
        s_hi[idx] = t;
    }
    __syncthreads();

    // ---- Thread mapping
    const int px = tid % PPB;
    const int fh = (tid / PPB) % FS;
    const int og = tid / (PPB * FS);
    const int phl = px / PW, pw = px % PW;
    const int o0 = osb * OPB + og * GO;

    float acc[GO][4];
#pragma unroll
    for (int g = 0; g < GO; ++g)
#pragma unroll
        for (int p = 0; p < 4; ++p) acc[g][p] = 0.f;

    const int pbase = (2 * phl) * (2 * CP) + pw;

#pragma unroll 1
    for (int cc = 0; cc < CS; ++cc) {
        const int c = fh * CS + cc;
        const float4* plo = s_lo + c * CPLANE;
        const W3*     phi = s_hi + c * CPLANE;
#pragma unroll 1
        for (int ky = 0; ky < 3; ++ky) {
#pragma unroll 1
            for (int kx = 0; kx < 3; ++kx) {
                const int f = c * 9 + ky * 3 + kx;
                const float4* wp = (const float4*)wrec + (size_t)(f * O + o0) * 2;
                float4 wl[GO];
                float  whx[GO], why[GO], whz[GO];
#pragma unroll
                for (int g = 0; g < GO; ++g) {
                    wl[g] = wp[g * 2];
                    float4 hv = wp[g * 2 + 1];
                    whx[g] = hv.x; why[g] = hv.y; whz[g] = hv.z;
                }
#pragma unroll
                for (int dy = 0; dy < 2; ++dy) {
#pragma unroll
                    for (int dx = 0; dx < 2; ++dx) {
                        const int s = dx + kx;
                        const int off = pbase + ((dy + ky) * 2 + (s & 1)) * CP + (s >> 1);
                        float4 lo = plo[off];
                        W3     hi = phi[off];
#pragma unroll
                        for (int g = 0; g < GO; ++g) {
                            acc[g][dy * 2 + dx] +=
                                lo.x * wl[g].x + lo.y * wl[g].y + lo.z * wl[g].z +
                                lo.w * wl[g].w + hi.x * whx[g] + hi.y * why[g] +
                                hi.z * whz[g];
                        }
                    }
                }
            }
        }
    }

    // ---- f-split reduction (reduce buffer aliases the act arena)
    if (FS > 1) {
        float4* s_red = (float4*)s_mem;
        __syncthreads();                   // act reads done before overwrite
#pragma unroll
        for (int g = 0; g < GO; ++g)
            s_red[g * NT + tid] = make_float4(acc[g][0], acc[g][1], acc[g][2], acc[g][3]);
        __syncthreads();
        if (fh != 0) return;
#pragma unroll
        for (int fq = 1; fq < FS; ++fq)
#pragma unroll
            for (int g = 0; g < GO; ++g) {
                float4 t = s_red[g * NT + tid + fq * PPB];
                acc[g][0] += t.x; acc[g][1] += t.y; acc[g][2] += t.z; acc[g][3] += t.w;
            }
    }

    // ---- maxpool + store
    const int phg = v * PR + phl;
#pragma unroll
    for (int g = 0; g < GO; ++g) {
        float m = fmaxf(fmaxf(acc[g][0], acc[g][1]), fmaxf(acc[g][2], acc[g][3]));
        out[(((size_t)b * O + o0 + g) * PH + phg) * PW + pw] = m;
    }
}

// out[n,o] = dot(h[n,:512], w[o,:512]) + bias[o]
__global__ __launch_bounds__(256) void linear_kernel(const float* __restrict__ h,
                                                     const float* __restrict__ w,
                                                     const float* __restrict__ bias,
                                                     float* __restrict__ out) {
    int idx = blockIdx.x * blockDim.x + threadIdx.x;
    if (idx >= BATCH * 100) return;
    int o = idx % 100;
    int n = idx / 100;
    const float4* hp = (const float4*)(h + (size_t)n * 512);
    const float4* wp = (const float4*)(w + (size_t)o * 512);
    float acc = 0.f;
#pragma unroll 4
    for (int i = 0; i < 128; ++i) {
        float4 a = hp[i];
        float4 b = wp[i];
        acc += a.x * b.x + a.y * b.y + a.z * b.z + a.w * b.w;
    }
    out[idx] = acc + bias[o];
}

extern "C" void kernel_launch(void* const* d_in, const int* in_sizes, int n_in,
                              void* d_out, int out_size, void* d_ws, size_t ws_size,
                              hipStream_t stream) {
    const float* x     = (const float*)d_in[0];
    const float* c1_bw = (const float*)d_in[1];
    const float* c1_sw = (const float*)d_in[2];
    const float* c1_sc = (const float*)d_in[3];
    const float* c2_bw = (const float*)d_in[4];
    const float* c2_sw = (const float*)d_in[5];
    const float* c2_sc = (const float*)d_in[6];
    const float* c3_bw = (const float*)d_in[7];
    const float* c3_sw = (const float*)d_in[8];
    const float* c3_sc = (const float*)d_in[9];
    const float* lin_w = (const float*)d_in[10];
    const float* lin_b = (const float*)d_in[11];
    float* out = (float*)d_out;

    float* ws = (float*)d_ws;
    float* h1 = ws;                 // 256*8*16*16  = 524288
    float* h2 = h1 + 524288;        // 256*16*8*8   = 262144
    float* h3 = h2 + 262144;        // 256*32*4*4   = 131072
    float* w1 = h3 + 131072;        // 216*8  = 1728
    float* w2 = w1 + 1728;          // 1152*8 = 9216
    float* w3 = w2 + 9216;          // 4608*8 = 36864
    // total 965312 floats = 3.9 MB

    // Fused weight records (independent; launch first).
    prep_weights<<<24, 256, 0, stream>>>(
        c1_bw, c1_sw, c1_sc, c2_bw, c2_sw, c2_sc, c3_bw, c3_sw, c3_sc, w1, w2, w3);

    // L1: [256,3,32,32] -> [256,8,16,16]; GO=4, FS=3, NT=768 (12 waves/blk).
    kan_conv_pool<3, 8, 4, 32, 32, 2, 1, 3, 768, 4><<<512, 768, 0, stream>>>(x, w1, h1);
    // L2: [256,8,16,16] -> [256,16,8,8]; GO=4, FS=4, NT=512; 2 blk/CU = 4/SIMD.
    kan_conv_pool<8, 16, 4, 16, 16, 2, 1, 4, 512, 4><<<512, 512, 0, stream>>>(h1, w2, h2);
    // L3: [256,16,8,8] -> [256,32,4,4]; OS=2, GO=4, FS=8, NT=512; 2 blk/CU = 4/SIMD.
    kan_conv_pool<16, 32, 4, 8, 8, 1, 2, 8, 512, 4><<<512, 512, 0, stream>>>(h2, w3, h3);
    // Linear: [256,512] @ [100,512]^T + b.
    linear_kernel<<<100, 256, 0, stream>>>(h3, lin_w, lin_b, out);
}